// Round 8
// baseline (1736.844 us; speedup 1.0000x reference)
//
#include <hip/hip_runtime.h>

typedef _Float16 half_t;
typedef _Float16 half8 __attribute__((ext_vector_type(8)));
typedef _Float16 half4 __attribute__((ext_vector_type(4)));
typedef _Float16 half16 __attribute__((ext_vector_type(16)));
typedef float float4v __attribute__((ext_vector_type(4)));
typedef unsigned uint4v __attribute__((ext_vector_type(4)));
typedef unsigned long long u64;

constexpr int NB = 64;    // batch
constexpr int NT = 50;    // steps
constexpr int NS = 256;   // state dim
constexpr int NA = 64;    // action dim
constexpr int NH = 256;   // hypernet hidden

constexpr float LO_SCALE = 2048.0f;
constexpr float LO_INV   = 1.0f / 2048.0f;

// ---- coherent-point access helpers (bypass per-XCD L2: no 128B-line staleness) ----
__device__ __forceinline__ unsigned aload32(const void* p) {
  return __hip_atomic_load((const unsigned*)p, __ATOMIC_RELAXED, __HIP_MEMORY_SCOPE_SYSTEM);
}
__device__ __forceinline__ void astore32(void* p, unsigned v) {
  __hip_atomic_store((unsigned*)p, v, __ATOMIC_RELAXED, __HIP_MEMORY_SCOPE_SYSTEM);
}
__device__ __forceinline__ void astoref(void* p, float v) {
  union { float f; unsigned u; } F; F.f = v;
  astore32(p, F.u);
}
__device__ __forceinline__ float aloadf(const void* p) {
  union { float f; unsigned u; } F; F.u = aload32(p);
  return F.f;
}
#define WAITVM() asm volatile("s_waitcnt vmcnt(0)" ::: "memory")
#define CFENCE() asm volatile("" ::: "memory")

// ---------------- preprocess kernels ----------------

__global__ void k_zero(unsigned* __restrict__ p, int n) {
  int idx = blockIdx.x * 256 + threadIdx.x;
  if (idx < n) p[idx] = 0u;
}

__global__ void k_hahb(const float* __restrict__ ctx, const float* __restrict__ W1a,
                       const float* __restrict__ b1a, const float* __restrict__ W1b,
                       const float* __restrict__ b1b, float* __restrict__ HA,
                       float* __restrict__ HB) {
  int tb = blockIdx.x;
  int t = tb / NB, b = tb % NB;
  int h = threadIdx.x;
  float z = ctx[b] + (float)t / 50.0f;
  HA[(size_t)tb * NH + h] = tanhf(z * W1a[h] + b1a[h]);
  HB[(size_t)tb * NH + h] = tanhf(z * W1b[h] + b1b[h]);
}

// V folded directly into Yq[t][i][b]
__global__ void k_v(const float* __restrict__ b2b, const float* __restrict__ us,
                    float* __restrict__ Yq) {
  int tb = blockIdx.x;
  int t = tb / NB, b = tb % NB;
  int i = threadIdx.x;
  __shared__ float ush[NA];
  if (i < NA) ush[i] = us[((size_t)b * NT + t) * NA + i];
  __syncthreads();
  const float* row = b2b + (size_t)i * NA;
  float s = 0.f;
#pragma unroll 8
  for (int j = 0; j < NA; ++j) s += row[j] * ush[j];
  Yq[((size_t)t * NS + i) * NB + b] = s;
}

// W2a lo split only: [h][i*NS+k] fp32 -> Wal [i][h][k] = (w - fp16(w))*2048
__global__ void k_wal(const float* __restrict__ W2a, half_t* __restrict__ Wal) {
  int i = blockIdx.x;
  int kq = (threadIdx.x & 63) * 4;
  int hs = threadIdx.x >> 6;
  for (int h0 = 0; h0 < NS; h0 += 4) {
    int h = h0 + hs;
    float4v v = *(const float4v*)(W2a + (size_t)h * (NS * NS) + (size_t)i * NS + kq);
    half4 ol;
#pragma unroll
    for (int r = 0; r < 4; ++r) {
      half_t hi = (half_t)v[r];
      ol[r] = (half_t)((v[r] - (float)hi) * LO_SCALE);
    }
    *(half4*)(Wal + ((size_t)i * NS + h) * NS + kq) = ol;
  }
}

__global__ void k_permb(const float* __restrict__ W2b, half_t* __restrict__ Wbh,
                        half_t* __restrict__ Wbl) {
  int i = blockIdx.x;
  int jq = (threadIdx.x & 15) * 4;
  int hh = threadIdx.x >> 4;
  for (int h0 = 0; h0 < NH; h0 += 16) {
    int h = h0 + hh;
    float4v v = *(const float4v*)(W2b + (size_t)h * (NS * NA) + (size_t)i * NA + jq);
    half4 oh, ol;
#pragma unroll
    for (int r = 0; r < 4; ++r) {
      half_t hi = (half_t)v[r];
      oh[r] = hi;
      ol[r] = (half_t)((v[r] - (float)hi) * LO_SCALE);
    }
    *(half4*)(Wbh + ((size_t)i * NH + h) * NA + jq) = oh;
    *(half4*)(Wbl + ((size_t)i * NH + h) * NA + jq) = ol;
  }
}

__global__ void k_u(const float* __restrict__ us, half_t* __restrict__ Uh,
                    half_t* __restrict__ Ul) {
  int t = blockIdx.x, tid = threadIdx.x;
  for (int r = 0; r < 16; ++r) {
    int idx = r * 256 + tid;
    int b = idx >> 6, j = idx & 63;
    float u = us[((size_t)b * NT + t) * NA + j];
    half_t hi = (half_t)u;
    Uh[((size_t)t * NB + b) * NA + j] = hi;
    Ul[((size_t)t * NB + b) * NA + j] = (half_t)((u - (float)hi) * LO_SCALE);
  }
}

// x0 -> XpS buffer 0, packed (hi | lo<<16)
__global__ void k_x0(const float* __restrict__ x0, unsigned* __restrict__ XpS) {
  size_t idx = (size_t)blockIdx.x * 256 + threadIdx.x;
  float x = x0[idx];
  half_t hi = (half_t)x;
  half_t lo = (half_t)((x - (float)hi) * LO_SCALE);
  union { half_t h[2]; unsigned u; } P;
  P.h[0] = hi; P.h[1] = lo;
  XpS[idx] = P.u;
}

// ---------------- persistent rollout ----------------
// grid=512: wg=(i=blk>>1, hh=blk&1), 256 thr (4 waves), 64 KiB static LDS (2 wg/CU).
// Wave wv owns b in [wv*16, wv*16+16) x the wg's 128 h-rows -> complete partials
// per wave, NO cross-wave combine, NO Y atomics.
// Phase 0: u-path for all t -> plain stores to Yp (hh=1) / Yq += (hh=0).
// Phase 1: hh=1 wave publishes partial (Ypub, system) + per-(i,wv) step-tag flag1;
// hh=0 wave polls flag1, reads Ypub via SYSTEM-SCOPE loads (128B-line staleness fix),
// finalizes its 16 b, publishes Xp; cnt->done->flag wake.
template <bool PRE>
__launch_bounds__(256, 2)
__global__ void k_roll(const float* __restrict__ W2a, const float* __restrict__ b2a,
                       const half_t* __restrict__ Wal, const half_t* __restrict__ Wbh,
                       const half_t* __restrict__ Wbl, const half_t* __restrict__ Uh,
                       const half_t* __restrict__ Ul, const float* __restrict__ HA,
                       const float* __restrict__ HB, unsigned* __restrict__ XpS,
                       float* __restrict__ Yp, float* __restrict__ Yq,
                       float* __restrict__ Ypub, unsigned* __restrict__ flag1,
                       unsigned* __restrict__ cnt, unsigned* __restrict__ done,
                       unsigned* __restrict__ flag, float* __restrict__ out) {
  __shared__ half_t Wlds[128 * 256];
  const int tid = threadIdx.x;
  const int i  = blockIdx.x >> 1;
  const int hh = blockIdx.x & 1;
  const int lane = tid & 63, wv = tid >> 6;
  const int l15 = lane & 15, quad = lane >> 4;
  const int b = wv * 16 + l15;            // this wave's batch column

  // --- stage W-hi half-slice into LDS from fp32 W2a (one-time), XOR swizzle
  for (int r = 0; r < 16; ++r) {
    int m = r * 256 + tid;
    int row = m >> 5, c = m & 31;
    const float* src = W2a + (size_t)(hh * 128 + row) * (NS * NS) + (size_t)i * NS + c * 8;
    float4v w0 = *(const float4v*)(src);
    float4v w1 = *(const float4v*)(src + 4);
    half8 v;
#pragma unroll
    for (int r4 = 0; r4 < 4; ++r4) { v[r4] = (half_t)w0[r4]; v[r4 + 4] = (half_t)w1[r4]; }
    *(half8*)(Wlds + row * 256 + ((c ^ (row & 7)) * 8)) = v;
  }
  __syncthreads();

  // ===== Phase 0: u-path for all t (no atomics; private partial buffers) =====
  for (int t = 0; t < NT; ++t) {
    float4v aU[8], aUc[8];
#pragma unroll
    for (int mt = 0; mt < 8; ++mt) {
      aU[mt] = (float4v){0.f, 0.f, 0.f, 0.f};
      aUc[mt] = (float4v){0.f, 0.f, 0.f, 0.f};
    }
#pragma unroll
    for (int kb = 0; kb < 2; ++kb) {
      const int jo = kb * 32 + quad * 8;
      half8 buh = *(const half8*)(Uh + ((size_t)t * NB + b) * NA + jo);
      half8 bul = *(const half8*)(Ul + ((size_t)t * NB + b) * NA + jo);
#pragma unroll
      for (int mt = 0; mt < 8; ++mt) {
        const int hg = hh * 128 + mt * 16 + l15;
        const size_t wb = ((size_t)i * NH + hg) * NA + jo;
        half8 auh = *(const half8*)(Wbh + wb);
        half8 aul = *(const half8*)(Wbl + wb);
        aU[mt]  = __builtin_amdgcn_mfma_f32_16x16x32_f16(auh, buh, aU[mt], 0, 0, 0);
        aUc[mt] = __builtin_amdgcn_mfma_f32_16x16x32_f16(auh, bul, aUc[mt], 0, 0, 0);
        aUc[mt] = __builtin_amdgcn_mfma_f32_16x16x32_f16(aul, buh, aUc[mt], 0, 0, 0);
      }
    }
    float pu = 0.f;
#pragma unroll
    for (int mt = 0; mt < 8; ++mt) {
      int hg = hh * 128 + mt * 16 + quad * 4;
      float4v hb4 = *(const float4v*)(HB + ((size_t)t * NB + b) * NH + hg);
#pragma unroll
      for (int r = 0; r < 4; ++r) pu += hb4[r] * (aU[mt][r] + aUc[mt][r] * LO_INV);
    }
    pu += __shfl_xor(pu, 16);
    pu += __shfl_xor(pu, 32);
    if (quad == 0) {
      size_t o = ((size_t)t * NS + i) * NB + b;
      if (hh == 1) Yp[o] = pu;
      else         Yq[o] += pu;        // Yq pre-loaded with V by k_v
    }
  }

  // ===== Phase 1: rollout =====
  for (int t = 0; t < NT; ++t) {
    if (t > 0) {
      if (wv == 0) {
        const unsigned* f = flag + ((size_t)(t - 1) * 8 + (blockIdx.x & 7)) * 32;
        while (aload32(f) == 0u) __builtin_amdgcn_s_sleep(2);
      }
      __syncthreads();
    }
    const unsigned* Xpc = XpS + (size_t)t * (NB * NS);   // fully published: cached loads

    float4v accA[8], accC[8];
#pragma unroll
    for (int mt = 0; mt < 8; ++mt) {
      accA[mt] = (float4v){0.f, 0.f, 0.f, 0.f};
      accC[mt] = (float4v){0.f, 0.f, 0.f, 0.f};
    }

#pragma unroll
    for (int kb = 0; kb < 8; ++kb) {
      const int ko = kb * 32 + quad * 8;
      const unsigned* q = Xpc + (size_t)b * NS + ko;
      union { uint4v u4[2]; half16 v; } U;
      U.u4[0] = *(const uint4v*)(q);
      U.u4[1] = *(const uint4v*)(q + 4);
      half8 bhi = __builtin_shufflevector(U.v, U.v, 0, 2, 4, 6, 8, 10, 12, 14);
      half8 blo = __builtin_shufflevector(U.v, U.v, 1, 3, 5, 7, 9, 11, 13, 15);
#pragma unroll
      for (int mt = 0; mt < 8; ++mt) {
        const int hloc = mt * 16 + l15;
        const int kc = kb * 4 + quad;
        half8 ahi = *(const half8*)(Wlds + hloc * 256 + ((kc ^ (hloc & 7)) * 8));
        half8 alo;
        if (PRE) {
          alo = *(const half8*)(Wal + (((size_t)i * NS) + hh * 128 + hloc) * NS + ko);
        } else {
          const float* src = W2a + (size_t)(hh * 128 + hloc) * (NS * NS) + (size_t)i * NS + ko;
          float4v w0 = *(const float4v*)(src);
          float4v w1 = *(const float4v*)(src + 4);
#pragma unroll
          for (int r4 = 0; r4 < 4; ++r4) {
            half_t h0v = (half_t)w0[r4];
            half_t h1v = (half_t)w1[r4];
            alo[r4]     = (half_t)((w0[r4] - (float)h0v) * LO_SCALE);
            alo[r4 + 4] = (half_t)((w1[r4] - (float)h1v) * LO_SCALE);
          }
        }
        accA[mt] = __builtin_amdgcn_mfma_f32_16x16x32_f16(ahi, bhi, accA[mt], 0, 0, 0);
        accC[mt] = __builtin_amdgcn_mfma_f32_16x16x32_f16(ahi, blo, accC[mt], 0, 0, 0);
        accC[mt] = __builtin_amdgcn_mfma_f32_16x16x32_f16(alo, bhi, accC[mt], 0, 0, 0);
      }
    }

    // ha-weighted reduce over this wg's 128 h -> complete per-wave partial for b
    float part = 0.f;
#pragma unroll
    for (int mt = 0; mt < 8; ++mt) {
      int hg = hh * 128 + mt * 16 + quad * 4;
      float4v ha4 = *(const float4v*)(HA + ((size_t)t * NB + b) * NH + hg);
#pragma unroll
      for (int r = 0; r < 4; ++r) part += ha4[r] * (accA[mt][r] + accC[mt][r] * LO_INV);
    }
    part += __shfl_xor(part, 16);
    part += __shfl_xor(part, 32);

    const size_t yo = ((size_t)t * NS + i) * NB + b;

    if (hh == 1) {
      // producer: publish partial(+u-part) and tag flag1
      if (quad == 0) astoref(Ypub + yo, part + Yp[yo]);
      WAITVM();
      if (lane == 0) astore32(flag1 + ((size_t)i * 4 + wv) * 16, (unsigned)(t + 1));
    } else {
      // bias: b2a_i . x_t for this wave's 16 b (lanes: quad = k-quarter)
      float bp = 0.f;
      {
        const float*    w  = b2a + (size_t)i * NS + quad * 64;
        const unsigned* xr = Xpc + (size_t)b * NS + quad * 64;
#pragma unroll
        for (int j = 0; j < 16; ++j) {
          float4v w4 = *(const float4v*)(w + j * 4);
          uint4v  xw = *(const uint4v*)(xr + j * 4);
#pragma unroll
          for (int r = 0; r < 4; ++r) {
            union { unsigned u; half_t h[2]; } P; P.u = xw[r];
            bp += w4[r] * ((float)P.h[0] + (float)P.h[1] * LO_INV);
          }
        }
      }
      bp += __shfl_xor(bp, 16);
      bp += __shfl_xor(bp, 32);

      // wait for partner wave's publication
      if (lane == 0) {
        const unsigned* f = flag1 + ((size_t)i * 4 + wv) * 16;
        while (aload32(f) < (unsigned)(t + 1)) __builtin_amdgcn_s_sleep(1);
      }
      CFENCE();

      if (quad == 0) {
        // SYSTEM-SCOPE read of Ypub: a plain load here can hit a stale 128B L2
        // line prematurely fetched by a sibling wave's miss (R7 bug).
        float ypub = aloadf(Ypub + yo);
        float xf = part + bp + ypub + Yq[yo];
        out[((size_t)b * NT + t) * NS + i] = xf;
        half_t hi = (half_t)xf;
        half_t lo = (half_t)((xf - (float)hi) * LO_SCALE);
        union { half_t h[2]; unsigned u; } P;
        P.h[0] = hi; P.h[1] = lo;
        astore32(XpS + (size_t)(t + 1) * (NB * NS) + (size_t)b * NS + i, P.u);
      }
      WAITVM();   // Xp (and out) drained before signaling
      unsigned old = 0;
      if (lane == 0) old = (unsigned)atomicAdd(&cnt[t * NS + i], 1u);
      old = (unsigned)__shfl((int)old, 0);
      if (old == 3u) {
        unsigned o2 = 0;
        if (lane == 0) o2 = (unsigned)atomicAdd(&done[t], 1u);
        o2 = (unsigned)__shfl((int)o2, 0);
        if (o2 == 255u && lane < 8)
          astore32(flag + ((size_t)t * 8 + lane) * 32, 1u);
      }
    }
  }
}

// ---------------- launch ----------------

extern "C" void kernel_launch(void* const* d_in, const int* in_sizes, int n_in,
                              void* d_out, int out_size, void* d_ws, size_t ws_size,
                              hipStream_t stream) {
  const float* x0  = (const float*)d_in[0];
  const float* ctx = (const float*)d_in[1];
  const float* us  = (const float*)d_in[2];
  const float* W1a = (const float*)d_in[3];
  const float* b1a = (const float*)d_in[4];
  const float* W2a = (const float*)d_in[5];
  const float* b2a = (const float*)d_in[6];
  const float* W1b = (const float*)d_in[7];
  const float* b1b = (const float*)d_in[8];
  const float* W2b = (const float*)d_in[9];
  const float* b2b = (const float*)d_in[10];
  float* out = (float*)d_out;

  const size_t szWa   = (size_t)NS * NS * NS * 2;        // 33,554,432 (Wal only)
  const size_t szWb   = (size_t)NS * NH * NA * 2;        //  8,388,608 each
  const size_t szU    = (size_t)NT * NB * NA * 2;        //    409,600 each
  const size_t szH    = (size_t)NT * NB * NH * 4;        //  3,276,800 each
  const size_t szXpS  = (size_t)(NT + 1) * NB * NS * 4;  //  3,342,336
  const size_t szYrow = (size_t)NT * NS * NB * 4;        //  3,276,800 each (Yp/Yq/Ypub)
  const size_t szCnt  = (size_t)NT * NS * 4;             //     51,200
  const size_t szDone = 256;
  const size_t szFlag = (size_t)NT * 8 * 32 * 4;         //     51,200
  const size_t szFlag1 = (size_t)NS * 4 * 16 * 4;        //     65,536

  const size_t fixed = szWb * 2 + szU * 2 + szH * 2 + szXpS + szYrow * 3 +
                       szCnt + szDone + szFlag + szFlag1;
  const bool pre = (ws_size >= fixed + szWa);

  char* p = (char*)d_ws;
  half_t* Wal = nullptr;
  if (pre) { Wal = (half_t*)p; p += szWa; }
  half_t* Wbh = (half_t*)p; p += szWb;
  half_t* Wbl = (half_t*)p; p += szWb;
  half_t* Uh  = (half_t*)p; p += szU;
  half_t* Ul  = (half_t*)p; p += szU;
  float*  HAg = (float*)p;  p += szH;
  float*  HBg = (float*)p;  p += szH;
  unsigned* XpS = (unsigned*)p; p += szXpS;
  float*  Yp  = (float*)p;  p += szYrow;
  float*  Yq  = (float*)p;  p += szYrow;
  float*  Ypub = (float*)p; p += szYrow;
  unsigned* cnt = (unsigned*)p; p += szCnt;      // zero block starts here
  unsigned* done = (unsigned*)p; p += szDone;
  unsigned* flag = (unsigned*)p; p += szFlag;
  unsigned* flag1 = (unsigned*)p;

  {
    int nwords = (int)((szCnt + szDone + szFlag + szFlag1) / 4);
    k_zero<<<(nwords + 255) / 256, 256, 0, stream>>>(cnt, nwords);
  }
  k_hahb<<<NT * NB, NH, 0, stream>>>(ctx, W1a, b1a, W1b, b1b, HAg, HBg);
  k_v<<<NT * NB, NS, 0, stream>>>(b2b, us, Yq);
  k_permb<<<NS, 256, 0, stream>>>(W2b, Wbh, Wbl);
  k_u<<<NT, 256, 0, stream>>>(us, Uh, Ul);
  k_x0<<<NB, NS, 0, stream>>>(x0, XpS);
  if (pre) k_wal<<<NS, 256, 0, stream>>>(W2a, Wal);

  void* args[] = {(void*)&W2a, (void*)&b2a, (void*)&Wal, (void*)&Wbh, (void*)&Wbl,
                  (void*)&Uh,  (void*)&Ul,  (void*)&HAg, (void*)&HBg, (void*)&XpS,
                  (void*)&Yp,  (void*)&Yq,  (void*)&Ypub, (void*)&flag1,
                  (void*)&cnt, (void*)&done, (void*)&flag, (void*)&out};

  hipError_t e;
  if (pre) {
    e = hipLaunchCooperativeKernel((void*)k_roll<true>, dim3(2 * NS), dim3(256), args, 0, stream);
    if (e != hipSuccess)
      k_roll<true><<<2 * NS, 256, 0, stream>>>(W2a, b2a, Wal, Wbh, Wbl, Uh, Ul,
                                               HAg, HBg, XpS, Yp, Yq, Ypub, flag1,
                                               cnt, done, flag, out);
  } else {
    e = hipLaunchCooperativeKernel((void*)k_roll<false>, dim3(2 * NS), dim3(256), args, 0, stream);
    if (e != hipSuccess)
      k_roll<false><<<2 * NS, 256, 0, stream>>>(W2a, b2a, Wal, Wbh, Wbl, Uh, Ul,
                                                HAg, HBg, XpS, Yp, Yq, Ypub, flag1,
                                                cnt, done, flag, out);
  }
}